// Round 4
// baseline (207.393 us; speedup 1.0000x reference)
//
#include <hip/hip_runtime.h>

// out[i] = -A * (x0^2 - x0 + x1^2 - x1) = x0*(1-x0) + x1*(1-x1)   (A = 1.0)
// Memory-bound elementwise map: 12 B/output (8 read + 4 write).
// Each thread: 4 outputs -> 2x 16B load, 1x nontemporal 16B store.

typedef float f32x4 __attribute__((ext_vector_type(4)));  // clang-native: OK for nontemporal builtins

__global__ void __launch_bounds__(256) poi2d_kernel(const float* __restrict__ in,
                                                    float* __restrict__ out,
                                                    int n_vec4) {
    const int stride = gridDim.x * blockDim.x;
    for (int v = blockIdx.x * blockDim.x + threadIdx.x; v < n_vec4; v += stride) {
        // v indexes a group of 4 outputs: outputs [4v, 4v+4), inputs floats [8v, 8v+8)
        const f32x4* in4 = reinterpret_cast<const f32x4*>(in) + 2 * (size_t)v;
        f32x4 a = in4[0];   // pairs (x0,x1) for outputs 4v, 4v+1
        f32x4 b = in4[1];   // pairs for outputs 4v+2, 4v+3
        f32x4 r;
        r.x = fmaf(a.x, 1.0f - a.x, a.y * (1.0f - a.y));
        r.y = fmaf(a.z, 1.0f - a.z, a.w * (1.0f - a.w));
        r.z = fmaf(b.x, 1.0f - b.x, b.y * (1.0f - b.y));
        r.w = fmaf(b.z, 1.0f - b.z, b.w * (1.0f - b.w));
        // Output is write-once, never re-read in the timed region: nontemporal
        // store keeps these lines from displacing input lines in L2/L3.
        __builtin_nontemporal_store(r, reinterpret_cast<f32x4*>(out) + v);
    }
}

// Tail kernel only needed if n % 4 != 0 (not the case for N=16777216, but safe).
__global__ void poi2d_tail_kernel(const float* __restrict__ in,
                                  float* __restrict__ out,
                                  int start, int n) {
    int i = start + blockIdx.x * blockDim.x + threadIdx.x;
    if (i < n) {
        float x0 = in[2 * (size_t)i];
        float x1 = in[2 * (size_t)i + 1];
        out[i] = fmaf(x0, 1.0f - x0, x1 * (1.0f - x1));
    }
}

extern "C" void kernel_launch(void* const* d_in, const int* in_sizes, int n_in,
                              void* d_out, int out_size, void* d_ws, size_t ws_size,
                              hipStream_t stream) {
    const float* in = (const float*)d_in[0];
    float* out = (float*)d_out;
    const int n = out_size;            // number of output rows (= N)
    const int n_vec4 = n / 4;

    const int block = 256;
    int grid = (n_vec4 + block - 1) / block;
    if (grid > 2048) grid = 2048;
    if (grid > 0) {
        poi2d_kernel<<<grid, block, 0, stream>>>(in, out, n_vec4);
    }

    const int tail_start = n_vec4 * 4;
    const int n_tail = n - tail_start;
    if (n_tail > 0) {
        int tgrid = (n_tail + block - 1) / block;
        poi2d_tail_kernel<<<tgrid, block, 0, stream>>>(in, out, tail_start, n);
    }
}

// Round 5
// 206.862 us; speedup vs baseline: 1.0026x; 1.0026x over previous
//
#include <hip/hip_runtime.h>

// out[i] = -A * (x0^2 - x0 + x1^2 - x1) = x0*(1-x0) + x1*(1-x1)   (A = 1.0)
// Memory-bound elementwise map: 12 B/output (8 read + 4 write).
// Each thread: 4 outputs -> 2x 16B load, 1x plain 16B store.
// Round-4 A/B: nontemporal store REMOVED (suspect: nt flag defeats L2
// write-combining on gfx950; harness fills with plain stores hit 6.9 TB/s).

typedef float f32x4 __attribute__((ext_vector_type(4)));

__global__ void __launch_bounds__(256) poi2d_kernel(const float* __restrict__ in,
                                                    float* __restrict__ out,
                                                    int n_vec4) {
    const int stride = gridDim.x * blockDim.x;
    for (int v = blockIdx.x * blockDim.x + threadIdx.x; v < n_vec4; v += stride) {
        // v indexes a group of 4 outputs: outputs [4v, 4v+4), inputs floats [8v, 8v+8)
        const f32x4* in4 = reinterpret_cast<const f32x4*>(in) + 2 * (size_t)v;
        f32x4 a = in4[0];   // pairs (x0,x1) for outputs 4v, 4v+1
        f32x4 b = in4[1];   // pairs for outputs 4v+2, 4v+3
        f32x4 r;
        r.x = fmaf(a.x, 1.0f - a.x, a.y * (1.0f - a.y));
        r.y = fmaf(a.z, 1.0f - a.z, a.w * (1.0f - a.w));
        r.z = fmaf(b.x, 1.0f - b.x, b.y * (1.0f - b.y));
        r.w = fmaf(b.z, 1.0f - b.z, b.w * (1.0f - b.w));
        reinterpret_cast<f32x4*>(out)[v] = r;   // plain store through L2
    }
}

// Tail kernel only needed if n % 4 != 0 (not the case for N=16777216, but safe).
__global__ void poi2d_tail_kernel(const float* __restrict__ in,
                                  float* __restrict__ out,
                                  int start, int n) {
    int i = start + blockIdx.x * blockDim.x + threadIdx.x;
    if (i < n) {
        float x0 = in[2 * (size_t)i];
        float x1 = in[2 * (size_t)i + 1];
        out[i] = fmaf(x0, 1.0f - x0, x1 * (1.0f - x1));
    }
}

extern "C" void kernel_launch(void* const* d_in, const int* in_sizes, int n_in,
                              void* d_out, int out_size, void* d_ws, size_t ws_size,
                              hipStream_t stream) {
    const float* in = (const float*)d_in[0];
    float* out = (float*)d_out;
    const int n = out_size;            // number of output rows (= N)
    const int n_vec4 = n / 4;

    const int block = 256;
    int grid = (n_vec4 + block - 1) / block;
    if (grid > 2048) grid = 2048;
    if (grid > 0) {
        poi2d_kernel<<<grid, block, 0, stream>>>(in, out, n_vec4);
    }

    const int tail_start = n_vec4 * 4;
    const int n_tail = n - tail_start;
    if (n_tail > 0) {
        int tgrid = (n_tail + block - 1) / block;
        poi2d_tail_kernel<<<tgrid, block, 0, stream>>>(in, out, tail_start, n);
    }
}

// Round 9
// 204.947 us; speedup vs baseline: 1.0119x; 1.0093x over previous
//
#include <hip/hip_runtime.h>

// out[i] = -A * (x0^2 - x0 + x1^2 - x1) = x0*(1-x0) + x1*(1-x1)   (A = 1.0)
// Memory-bound elementwise map: 12 B/output (8 read + 4 write).
// Exact-grid launch (no grid-stride loop): one vec4-group (4 outputs) per
// thread -> 2x 16B coalesced loads + 1x 16B coalesced store, same dispatch
// shape as the harness fills that sustain 6.9 TB/s.

typedef float f32x4 __attribute__((ext_vector_type(4)));

__global__ void __launch_bounds__(256) poi2d_kernel(const float* __restrict__ in,
                                                    float* __restrict__ out,
                                                    int n_vec4) {
    const int v = blockIdx.x * blockDim.x + threadIdx.x;
    if (v < n_vec4) {
        const f32x4* in4 = reinterpret_cast<const f32x4*>(in) + 2 * (size_t)v;
        f32x4 a = in4[0];   // pairs (x0,x1) for outputs 4v, 4v+1
        f32x4 b = in4[1];   // pairs for outputs 4v+2, 4v+3
        f32x4 r;
        r.x = fmaf(a.x, 1.0f - a.x, a.y * (1.0f - a.y));
        r.y = fmaf(a.z, 1.0f - a.z, a.w * (1.0f - a.w));
        r.z = fmaf(b.x, 1.0f - b.x, b.y * (1.0f - b.y));
        r.w = fmaf(b.z, 1.0f - b.z, b.w * (1.0f - b.w));
        reinterpret_cast<f32x4*>(out)[v] = r;
    }
}

// Tail kernel only needed if n % 4 != 0 (not the case for N=16777216, but safe).
__global__ void poi2d_tail_kernel(const float* __restrict__ in,
                                  float* __restrict__ out,
                                  int start, int n) {
    int i = start + blockIdx.x * blockDim.x + threadIdx.x;
    if (i < n) {
        float x0 = in[2 * (size_t)i];
        float x1 = in[2 * (size_t)i + 1];
        out[i] = fmaf(x0, 1.0f - x0, x1 * (1.0f - x1));
    }
}

extern "C" void kernel_launch(void* const* d_in, const int* in_sizes, int n_in,
                              void* d_out, int out_size, void* d_ws, size_t ws_size,
                              hipStream_t stream) {
    const float* in = (const float*)d_in[0];
    float* out = (float*)d_out;
    const int n = out_size;            // number of output rows (= N)
    const int n_vec4 = n / 4;

    const int block = 256;
    const int grid = (n_vec4 + block - 1) / block;   // exact grid: 16384 blocks for N=2^24
    if (grid > 0) {
        poi2d_kernel<<<grid, block, 0, stream>>>(in, out, n_vec4);
    }

    const int tail_start = n_vec4 * 4;
    const int n_tail = n - tail_start;
    if (n_tail > 0) {
        int tgrid = (n_tail + block - 1) / block;
        poi2d_tail_kernel<<<tgrid, block, 0, stream>>>(in, out, tail_start, n);
    }
}